// Round 7
// baseline (381.235 us; speedup 1.0000x reference)
//
#include <hip/hip_runtime.h>
#include <hip/hip_bf16.h>

#define DEVINL __device__ __forceinline__

typedef __attribute__((ext_vector_type(4))) float f32x4;
typedef __attribute__((ext_vector_type(8))) short short8;

constexpr int CB = 2, CT = 2048, CD = 1024, CH = 16, CDK = 64;
constexpr int CM = CB * CT; // 4096 rows
constexpr float LOG2E = 1.44269504088896340736f;

DEVINL ushort f2bf(float f) {
  __hip_bfloat16 h = __float2bfloat16(f); // RNE
  ushort u; __builtin_memcpy(&u, &h, 2); return u;
}

// ---------------- fused f32 -> bf16 convert (all 6 tensors, one launch) ----------------
__global__ void cvt_all_kernel(const float* __restrict__ s0, ushort* __restrict__ d0, int n0,
                               const float* __restrict__ s1, ushort* __restrict__ d1, int n1,
                               const float* __restrict__ s2, ushort* __restrict__ d2, int n2,
                               const float* __restrict__ s3, ushort* __restrict__ d3, int n3,
                               const float* __restrict__ s4, ushort* __restrict__ d4, int n4,
                               const float* __restrict__ s5, ushort* __restrict__ d5, int n5)
{
  int i = (blockIdx.x * blockDim.x + threadIdx.x) * 4;
  const float* s; ushort* d;
  if (i < n0) { s = s0; d = d0; }
  else if ((i -= n0) < n1) { s = s1; d = d1; }
  else if ((i -= n1) < n2) { s = s2; d = d2; }
  else if ((i -= n2) < n3) { s = s3; d = d3; }
  else if ((i -= n3) < n4) { s = s4; d = d4; }
  else if ((i -= n4) < n5) { s = s5; d = d5; }
  else return;
  float4 v = *reinterpret_cast<const float4*>(s + i);
  ushort4 o;
  o.x = f2bf(v.x); o.y = f2bf(v.y); o.z = f2bf(v.z); o.w = f2bf(v.w);
  *reinterpret_cast<ushort4*>(d + i) = o;
}

// ---------------- mask -> per-64x64-tile all-valid flags ----------------
__global__ void mask_flags_kernel(const int* __restrict__ mask, uint* __restrict__ flags) {
  const int tile = blockIdx.x;              // 2048 tiles
  const int b = tile >> 10, qb = (tile >> 5) & 31, kb = tile & 31;
  const int* base = mask + ((size_t)b * CT + qb * 64) * CT + kb * 64;
  const int r = threadIdx.x >> 2, c0 = (threadIdx.x & 3) * 16;
  int ok = 1;
  for (int j = 0; j < 4; ++j) {
    int4 v = *reinterpret_cast<const int4*>(base + (size_t)r * CT + c0 + j * 4);
    ok &= (v.x != 0) & (v.y != 0) & (v.z != 0) & (v.w != 0);
  }
  __shared__ int red[4];
  unsigned long long bal = __ballot(ok);
  if ((threadIdx.x & 63) == 0) red[threadIdx.x >> 6] = (bal == ~0ull);
  __syncthreads();
  if (threadIdx.x == 0) flags[tile] = (uint)(red[0] & red[1] & red[2] & red[3]);
}

// ---------------- NT GEMM (padded-LDS structure) ----------------
// mode 0: store bf16 to (B,H,T,DK); mode 1: store bf16 to (B,H,DK,T); mode 2: f32 row-major
__global__ __launch_bounds__(256, 2)
void gemm_nt_kernel(const ushort* __restrict__ A, const ushort* __restrict__ Bm,
                    const float* __restrict__ bias, void* __restrict__ Out,
                    int M, int N, int K, int mode, float scale)
{
  constexpr int BM = 128, BN = 128, BK = 32, LDT = 40;
  __shared__ __align__(16) ushort As[BM * LDT];
  __shared__ __align__(16) ushort Bs[BN * LDT];
  const int tid = threadIdx.x;
  const int lane = tid & 63, wid = tid >> 6;
  const int wr = wid >> 1, wc = wid & 1;
  const int bm0 = blockIdx.y * BM, bn0 = blockIdx.x * BN;
  const int rsel = lane & 15, ksel = (lane >> 4) * 8;
  const int lrow = tid >> 2, lg = (tid & 3) * 8;

  f32x4 acc[4][4];
  for (int i = 0; i < 4; ++i) for (int j = 0; j < 4; ++j) acc[i][j] = f32x4{0.f, 0.f, 0.f, 0.f};

  for (int k0 = 0; k0 < K; k0 += BK) {
    __syncthreads();
    for (int p = 0; p < 2; ++p) {
      int r = p * 64 + lrow;
      *reinterpret_cast<short8*>(&As[r * LDT + lg]) =
          *reinterpret_cast<const short8*>(&A[(size_t)(bm0 + r) * K + k0 + lg]);
      *reinterpret_cast<short8*>(&Bs[r * LDT + lg]) =
          *reinterpret_cast<const short8*>(&Bm[(size_t)(bn0 + r) * K + k0 + lg]);
    }
    __syncthreads();
    short8 af[4], bfr[4];
    for (int mi = 0; mi < 4; ++mi)
      af[mi] = *reinterpret_cast<short8*>(&As[(wr * 64 + mi * 16 + rsel) * LDT + ksel]);
    for (int ni = 0; ni < 4; ++ni)
      bfr[ni] = *reinterpret_cast<short8*>(&Bs[(wc * 64 + ni * 16 + rsel) * LDT + ksel]);
    for (int mi = 0; mi < 4; ++mi)
      for (int ni = 0; ni < 4; ++ni)
        acc[mi][ni] = __builtin_amdgcn_mfma_f32_16x16x32_bf16(af[mi], bfr[ni], acc[mi][ni], 0, 0, 0);
  }

  const int r0 = (lane >> 4) * 4;
  for (int mi = 0; mi < 4; ++mi)
    for (int ni = 0; ni < 4; ++ni) {
      int gj = bn0 + wc * 64 + ni * 16 + rsel;
      float bv = bias[gj];
      for (int r = 0; r < 4; ++r) {
        int gi = bm0 + wr * 64 + mi * 16 + r0 + r;
        float v = (acc[mi][ni][r] + bv) * scale;
        if (mode == 2) {
          reinterpret_cast<float*>(Out)[(size_t)gi * N + gj] = v;
        } else {
          int bb = gi >> 11, t = gi & (CT - 1), h = gj >> 6, dk = gj & 63;
          size_t idx = (mode == 0)
              ? (((size_t)(bb * CH + h) * CT + t) * CDK + dk)
              : (((size_t)(bb * CH + h) * CDK + dk) * CT + t);
          reinterpret_cast<ushort*>(Out)[idx] = f2bf(v);
        }
      }
    }
}

// ---------------- lsum: L[q] partials = sum_k exp2(S[q,k]) via 128x128 tiles ----------------
// grid: (T/128, B*H). 4 waves (2x2). Deterministic: wave-column wc writes Lws[wc][bh*T+q].
__global__ __launch_bounds__(256, 2)
void lsum_kernel(const ushort* __restrict__ Qb, const ushort* __restrict__ Kb,
                 const int* __restrict__ mask, const uint* __restrict__ flags,
                 float* __restrict__ Lws)
{
  constexpr int LDT = 72;
  __shared__ __align__(16) ushort Qs[128 * LDT];
  __shared__ __align__(16) ushort Ks[128 * LDT];
  const int tid = threadIdx.x, lane = tid & 63, wid = tid >> 6;
  const int wr = wid >> 1, wc = wid & 1;
  const int bh = blockIdx.y, b = bh >> 4;
  const int q0 = blockIdx.x * 128;
  const int rsel = lane & 15, grp = lane >> 4, ksel = grp * 8;
  const int srow = tid >> 3, scol = (tid & 7) * 8;

  // stage Q tile once (128 x 64)
  for (int p = 0; p < 4; ++p) {
    int r = p * 32 + srow;
    *reinterpret_cast<short8*>(&Qs[r * LDT + scol]) =
        *reinterpret_cast<const short8*>(&Qb[((size_t)bh * CT + q0 + r) * CDK + scol]);
  }
  __syncthreads();
  short8 qa0[4], qa1[4];
  for (int mi = 0; mi < 4; ++mi) {
    qa0[mi] = *reinterpret_cast<short8*>(&Qs[(wr * 64 + mi * 16 + rsel) * LDT + ksel]);
    qa1[mi] = *reinterpret_cast<short8*>(&Qs[(wr * 64 + mi * 16 + rsel) * LDT + 32 + ksel]);
  }

  float lsum[4][4];
  for (int mi = 0; mi < 4; ++mi) for (int r = 0; r < 4; ++r) lsum[mi][r] = 0.f;
  const int* mrow = mask + (size_t)b * CT * CT;
  const uint* fl = flags + (b << 10) + ((q0 >> 6) + wr) * 32;

  for (int kt = 0; kt < 16; ++kt) {
    __syncthreads();
    for (int p = 0; p < 4; ++p) {
      int r = p * 32 + srow;
      *reinterpret_cast<short8*>(&Ks[r * LDT + scol]) =
          *reinterpret_cast<const short8*>(&Kb[((size_t)bh * CT + kt * 128 + r) * CDK + scol]);
    }
    __syncthreads();
    const uint f = fl[kt * 2 + wc];
    for (int ni = 0; ni < 4; ++ni) {
      short8 kb0 = *reinterpret_cast<short8*>(&Ks[(wc * 64 + ni * 16 + rsel) * LDT + ksel]);
      short8 kb1 = *reinterpret_cast<short8*>(&Ks[(wc * 64 + ni * 16 + rsel) * LDT + 32 + ksel]);
      for (int mi = 0; mi < 4; ++mi) {
        f32x4 z = {0.f, 0.f, 0.f, 0.f};
        z = __builtin_amdgcn_mfma_f32_16x16x32_bf16(qa0[mi], kb0, z, 0, 0, 0);
        z = __builtin_amdgcn_mfma_f32_16x16x32_bf16(qa1[mi], kb1, z, 0, 0, 0);
        if (f) {
          for (int r = 0; r < 4; ++r) lsum[mi][r] += exp2f(z[r]);
        } else {
          int k = kt * 128 + wc * 64 + ni * 16 + rsel;
          for (int r = 0; r < 4; ++r) {
            int q = q0 + wr * 64 + mi * 16 + grp * 4 + r;
            lsum[mi][r] += mrow[(size_t)q * CT + k] ? exp2f(z[r]) : 0.f;
          }
        }
      }
    }
  }
  // reduce across the 16 rsel lanes (columns); grp preserved
  for (int off = 1; off < 16; off <<= 1)
    for (int mi = 0; mi < 4; ++mi)
      for (int r = 0; r < 4; ++r) lsum[mi][r] += __shfl_xor(lsum[mi][r], off, 64);
  if (rsel == 0) {
    float* Lout = Lws + (size_t)wc * (CB * CH * CT) + (size_t)bh * CT;
    for (int mi = 0; mi < 4; ++mi)
      for (int r = 0; r < 4; ++r)
        Lout[q0 + wr * 64 + mi * 16 + grp * 4 + r] = lsum[mi][r];
  }
}

// ---------------- fused attention, single pass (uses precomputed L) ----------------
// grid: (T/128, B*H), 8 waves. Qb has 0.125*log2e folded in. Vt: (B,H,DK,T).
__global__ __launch_bounds__(512, 2)
void attn_kernel(const ushort* __restrict__ Qb, const ushort* __restrict__ Kb,
                 const ushort* __restrict__ Vt, const int* __restrict__ mask,
                 const uint* __restrict__ flags, const float* __restrict__ Lws,
                 float* __restrict__ attn_out, ushort* __restrict__ oh)
{
  constexpr int KB = 64, LDK = 72;
  __shared__ __align__(16) ushort Ks[KB * LDK];
  __shared__ __align__(16) ushort Vs[CDK * LDK];
  __shared__ __align__(16) ushort Ps[8][16 * LDK];

  const int tid = threadIdx.x, wid = tid >> 6, lane = tid & 63;
  const int bh = blockIdx.y, b = bh >> 4, h = bh & 15;
  const int q0 = blockIdx.x * 128 + wid * 16;
  const int rsel = lane & 15, grp = lane >> 4, ksel = grp * 8;
  const int srow = tid >> 3, scol = (tid & 7) * 8;
  const uint* fl = flags + (b << 10) + ((q0 >> 6) << 5);

  short8 qa0, qa1;
  {
    const ushort* qrow = Qb + ((size_t)bh * CT + q0 + rsel) * CDK;
    qa0 = *reinterpret_cast<const short8*>(qrow + ksel);
    qa1 = *reinterpret_cast<const short8*>(qrow + 32 + ksel);
  }

  // per-row inverse denominators (two deterministic partials)
  float inv_l[4];
  {
    const float* L0 = Lws + (size_t)bh * CT;
    const float* L1 = Lws + (size_t)(CB * CH) * CT + (size_t)bh * CT;
    for (int r = 0; r < 4; ++r) {
      int q = q0 + grp * 4 + r;
      inv_l[r] = 1.f / (L0[q] + L1[q]);
    }
  }

  f32x4 oacc[4];
  for (int nd = 0; nd < 4; ++nd) oacc[nd] = f32x4{0.f, 0.f, 0.f, 0.f};
  float* arow = attn_out + (size_t)bh * CT * CT;
  const int* mrow = mask + (size_t)b * CT * CT;
  ushort* pw = &Ps[wid][0];

  for (int k0 = 0; k0 < CT; k0 += KB) {
    __syncthreads();
    *reinterpret_cast<short8*>(&Ks[srow * LDK + scol]) =
        *reinterpret_cast<const short8*>(&Kb[((size_t)bh * CT + k0 + srow) * CDK + scol]);
    *reinterpret_cast<short8*>(&Vs[srow * LDK + scol]) =
        *reinterpret_cast<const short8*>(&Vt[((size_t)bh * CDK + srow) * CT + k0 + scol]);
    __syncthreads();
    const uint f = fl[k0 >> 6];
    for (int ni = 0; ni < 4; ++ni) {
      f32x4 z = {0.f, 0.f, 0.f, 0.f};
      short8 kb0 = *reinterpret_cast<short8*>(&Ks[(ni * 16 + rsel) * LDK + ksel]);
      short8 kb1 = *reinterpret_cast<short8*>(&Ks[(ni * 16 + rsel) * LDK + 32 + ksel]);
      z = __builtin_amdgcn_mfma_f32_16x16x32_bf16(qa0, kb0, z, 0, 0, 0);
      z = __builtin_amdgcn_mfma_f32_16x16x32_bf16(qa1, kb1, z, 0, 0, 0);
      int kk = k0 + ni * 16 + rsel;
      for (int r = 0; r < 4; ++r) {
        int q = q0 + grp * 4 + r;
        float p;
        if (f) p = exp2f(z[r]);
        else   p = mrow[(size_t)q * CT + kk] ? exp2f(z[r]) : 0.f;
        arow[(size_t)q * CT + kk] = p * inv_l[r];
        pw[(grp * 4 + r) * LDK + ni * 16 + rsel] = f2bf(p);
      }
    }
    short8 pa0 = *reinterpret_cast<short8*>(&pw[rsel * LDK + ksel]);
    short8 pa1 = *reinterpret_cast<short8*>(&pw[rsel * LDK + 32 + ksel]);
    for (int nd = 0; nd < 4; ++nd) {
      short8 vb0 = *reinterpret_cast<short8*>(&Vs[(nd * 16 + rsel) * LDK + ksel]);
      short8 vb1 = *reinterpret_cast<short8*>(&Vs[(nd * 16 + rsel) * LDK + 32 + ksel]);
      oacc[nd] = __builtin_amdgcn_mfma_f32_16x16x32_bf16(pa0, vb0, oacc[nd], 0, 0, 0);
      oacc[nd] = __builtin_amdgcn_mfma_f32_16x16x32_bf16(pa1, vb1, oacc[nd], 0, 0, 0);
    }
  }

  for (int nd = 0; nd < 4; ++nd)
    for (int r = 0; r < 4; ++r) {
      int q = q0 + grp * 4 + r, d = nd * 16 + rsel;
      oh[((size_t)b * CT + q) * CD + h * CDK + d] = f2bf(oacc[nd][r] * inv_l[r]);
    }
}

// ---------------- launcher ----------------
extern "C" void kernel_launch(void* const* d_in, const int* in_sizes, int n_in,
                              void* d_out, int out_size, void* d_ws, size_t ws_size,
                              hipStream_t stream)
{
  const float* x_q  = (const float*)d_in[0];
  const float* x_kv = (const float*)d_in[1];
  const int*   mask = (const int*)d_in[2];
  const float* Wq = (const float*)d_in[3];
  const float* bq = (const float*)d_in[4];
  const float* Wk = (const float*)d_in[5];
  const float* bk = (const float*)d_in[6];
  const float* Wv = (const float*)d_in[7];
  const float* bv = (const float*)d_in[8];
  const float* Wo = (const float*)d_in[9];
  const float* bo = (const float*)d_in[10];

  float* out  = (float*)d_out;
  float* attn = out + (size_t)CB * CT * CD;

  char* w = (char*)d_ws;
  auto alloc = [&](size_t bytes) { char* p = w; w += (bytes + 255) & ~(size_t)255; return p; };
  ushort* xq_bf  = (ushort*)alloc((size_t)CM * CD * 2);
  ushort* xkv_bf = (ushort*)alloc((size_t)CM * CD * 2);
  ushort* Wq_bf  = (ushort*)alloc((size_t)CD * CD * 2);
  ushort* Wk_bf  = (ushort*)alloc((size_t)CD * CD * 2);
  ushort* Wv_bf  = (ushort*)alloc((size_t)CD * CD * 2);
  ushort* Wo_bf  = (ushort*)alloc((size_t)CD * CD * 2);
  ushort* Q_bf   = (ushort*)alloc((size_t)CM * CD * 2);
  ushort* K_bf   = (ushort*)alloc((size_t)CM * CD * 2);
  ushort* Vt_bf  = (ushort*)alloc((size_t)CM * CD * 2);
  ushort* oh_bf  = (ushort*)alloc((size_t)CM * CD * 2);
  uint*   mflags = (uint*)alloc(2048 * sizeof(uint));
  float*  Lws    = (float*)alloc((size_t)2 * CB * CH * CT * sizeof(float));

  {
    const int nx = CM * CD, nw = CD * CD;
    const int total_quads = (2 * nx + 4 * nw) / 4;
    const int blocks = (total_quads + 255) / 256;
    hipLaunchKernelGGL(cvt_all_kernel, dim3(blocks), dim3(256), 0, stream,
                       x_q, xq_bf, nx, x_kv, xkv_bf, nx,
                       Wq, Wq_bf, nw, Wk, Wk_bf, nw,
                       Wv, Wv_bf, nw, Wo, Wo_bf, nw);
  }

  hipLaunchKernelGGL(mask_flags_kernel, dim3(2048), dim3(256), 0, stream, mask, mflags);

  dim3 gproj(CD / 128, CM / 128); // (8, 32)
  hipLaunchKernelGGL(gemm_nt_kernel, gproj, dim3(256), 0, stream, xq_bf,  Wq_bf, bq, (void*)Q_bf,  CM, CD, CD, 0, 0.125f * LOG2E);
  hipLaunchKernelGGL(gemm_nt_kernel, gproj, dim3(256), 0, stream, xkv_bf, Wk_bf, bk, (void*)K_bf,  CM, CD, CD, 0, 1.0f);
  hipLaunchKernelGGL(gemm_nt_kernel, gproj, dim3(256), 0, stream, xkv_bf, Wv_bf, bv, (void*)Vt_bf, CM, CD, CD, 1, 1.0f);

  hipLaunchKernelGGL(lsum_kernel, dim3(CT / 128, CB * CH), dim3(256), 0, stream,
                     Q_bf, K_bf, mask, mflags, Lws);

  hipLaunchKernelGGL(attn_kernel, dim3(CT / 128, CB * CH), dim3(512), 0, stream,
                     Q_bf, K_bf, Vt_bf, mask, mflags, Lws, attn, oh_bf);

  hipLaunchKernelGGL(gemm_nt_kernel, gproj, dim3(256), 0, stream, oh_bf, Wo_bf, bo, d_out, CM, CD, CD, 2, 1.0f);
}

// Round 8
// 331.491 us; speedup vs baseline: 1.1501x; 1.1501x over previous
//
#include <hip/hip_runtime.h>
#include <hip/hip_bf16.h>

#define DEVINL __device__ __forceinline__

typedef __attribute__((ext_vector_type(4))) float f32x4;
typedef __attribute__((ext_vector_type(8))) short short8;

constexpr int CB = 2, CT = 2048, CD = 1024, CH = 16, CDK = 64;
constexpr int CM = CB * CT; // 4096 rows
constexpr float LOG2E = 1.44269504088896340736f;

DEVINL ushort f2bf(float f) {
  __hip_bfloat16 h = __float2bfloat16(f); // RNE
  ushort u; __builtin_memcpy(&u, &h, 2); return u;
}

DEVINL void gl2lds16(const ushort* g, ushort* ldsbase) {
  __builtin_amdgcn_global_load_lds(
      (const __attribute__((address_space(1))) void*)g,
      (__attribute__((address_space(3))) void*)ldsbase, 16, 0, 0);
}

// ---------------- fused f32 -> bf16 convert (all 6 tensors, one launch) ----------------
__global__ void cvt_all_kernel(const float* __restrict__ s0, ushort* __restrict__ d0, int n0,
                               const float* __restrict__ s1, ushort* __restrict__ d1, int n1,
                               const float* __restrict__ s2, ushort* __restrict__ d2, int n2,
                               const float* __restrict__ s3, ushort* __restrict__ d3, int n3,
                               const float* __restrict__ s4, ushort* __restrict__ d4, int n4,
                               const float* __restrict__ s5, ushort* __restrict__ d5, int n5)
{
  int i = (blockIdx.x * blockDim.x + threadIdx.x) * 4;
  const float* s; ushort* d;
  if (i < n0) { s = s0; d = d0; }
  else if ((i -= n0) < n1) { s = s1; d = d1; }
  else if ((i -= n1) < n2) { s = s2; d = d2; }
  else if ((i -= n2) < n3) { s = s3; d = d3; }
  else if ((i -= n3) < n4) { s = s4; d = d4; }
  else if ((i -= n4) < n5) { s = s5; d = d5; }
  else return;
  float4 v = *reinterpret_cast<const float4*>(s + i);
  ushort4 o;
  o.x = f2bf(v.x); o.y = f2bf(v.y); o.z = f2bf(v.z); o.w = f2bf(v.w);
  *reinterpret_cast<ushort4*>(d + i) = o;
}

// ---------------- mask -> per-64x64-tile all-valid flags ----------------
__global__ void mask_flags_kernel(const int* __restrict__ mask, uint* __restrict__ flags) {
  const int tile = blockIdx.x;              // 2048 tiles
  const int b = tile >> 10, qb = (tile >> 5) & 31, kb = tile & 31;
  const int* base = mask + ((size_t)b * CT + qb * 64) * CT + kb * 64;
  const int r = threadIdx.x >> 2, c0 = (threadIdx.x & 3) * 16;
  int ok = 1;
  for (int j = 0; j < 4; ++j) {
    int4 v = *reinterpret_cast<const int4*>(base + (size_t)r * CT + c0 + j * 4);
    ok &= (v.x != 0) & (v.y != 0) & (v.z != 0) & (v.w != 0);
  }
  __shared__ int red[4];
  unsigned long long bal = __ballot(ok);
  if ((threadIdx.x & 63) == 0) red[threadIdx.x >> 6] = (bal == ~0ull);
  __syncthreads();
  if (threadIdx.x == 0) flags[tile] = (uint)(red[0] & red[1] & red[2] & red[3]);
}

// ---------------- NT GEMM, 2-phase double-buffered global_load_lds ----------------
// C[i,j] = sum_k A[i,k]*Bm[j,k]. BM=128, BN=64, BK=32, linear LDS (dest of gl2lds).
// mode 0: bf16 -> (B,H,T,DK); mode 2: f32 row-major MxN;
// mode 3: KV-merged (N=2048): j<1024 -> K layout (B,H,T,DK) w/ bias1, j>=1024 -> Vt (B,H,DK,T) w/ bias2.
__global__ __launch_bounds__(256, 2)
void gemm_nt_kernel(const ushort* __restrict__ A, const ushort* __restrict__ Bm,
                    const float* __restrict__ bias1, const float* __restrict__ bias2,
                    void* __restrict__ Out, void* __restrict__ Out2,
                    int M, int N, int K, int mode, float scale)
{
  constexpr int BM = 128, BN = 64, BK = 32;
  __shared__ __align__(16) ushort As[2][BM * BK];
  __shared__ __align__(16) ushort Bs[2][BN * BK];
  const int tid = threadIdx.x;
  const int lane = tid & 63, wid = tid >> 6;
  const int wr = wid >> 1, wc = wid & 1;
  const int bm0 = blockIdx.y * BM, bn0 = blockIdx.x * BN;
  const int rsel = lane & 15, ksel = (lane >> 4) * 8;
  const int srow = lane >> 2, sc8 = (lane & 3) * 8; // within a 16-row wave-call

  f32x4 acc[4][2];
  for (int i = 0; i < 4; ++i) for (int j = 0; j < 2; ++j) acc[i][j] = f32x4{0.f, 0.f, 0.f, 0.f};

  // stage tile kt into buffer bu: per wave, A rows wid*32..+31 (2 calls), B rows wid*16..+15 (1 call)
  auto stage = [&](int bu, int k0) {
    const int ra0 = wid * 32;
    gl2lds16(&A[(size_t)(bm0 + ra0 + srow) * K + k0 + sc8],      &As[bu][ra0 * BK]);
    gl2lds16(&A[(size_t)(bm0 + ra0 + 16 + srow) * K + k0 + sc8], &As[bu][(ra0 + 16) * BK]);
    const int rb0 = wid * 16;
    gl2lds16(&Bm[(size_t)(bn0 + rb0 + srow) * K + k0 + sc8],     &Bs[bu][rb0 * BK]);
  };

  stage(0, 0);
  __syncthreads();
  const int NKT = K / BK;
  int bu = 0;
  for (int kt = 0; kt < NKT; ++kt) {
    if (kt + 1 < NKT) stage(bu ^ 1, (kt + 1) * BK); // prefetch overlaps compute below
    short8 af[4], bfr[2];
    for (int mi = 0; mi < 4; ++mi)
      af[mi] = *reinterpret_cast<short8*>(&As[bu][(wr * 64 + mi * 16 + rsel) * BK + ksel]);
    for (int ni = 0; ni < 2; ++ni)
      bfr[ni] = *reinterpret_cast<short8*>(&Bs[bu][(wc * 32 + ni * 16 + rsel) * BK + ksel]);
    for (int mi = 0; mi < 4; ++mi)
      for (int ni = 0; ni < 2; ++ni)
        acc[mi][ni] = __builtin_amdgcn_mfma_f32_16x16x32_bf16(af[mi], bfr[ni], acc[mi][ni], 0, 0, 0);
    if (kt + 1 < NKT) { __syncthreads(); bu ^= 1; } // vmcnt(0)+barrier: staged tile ready
  }

  const int r0 = (lane >> 4) * 4;
  for (int mi = 0; mi < 4; ++mi)
    for (int ni = 0; ni < 2; ++ni) {
      int gj = bn0 + wc * 32 + ni * 16 + rsel;
      float bv = (mode == 3 && gj >= 1024) ? bias2[gj - 1024] : bias1[gj];
      for (int r = 0; r < 4; ++r) {
        int gi = bm0 + wr * 64 + mi * 16 + r0 + r;
        float v = (acc[mi][ni][r] + bv) * scale;
        if (mode == 2) {
          reinterpret_cast<float*>(Out)[(size_t)gi * N + gj] = v;
        } else {
          int bb = gi >> 11, t = gi & (CT - 1);
          if (mode == 3 && gj >= 1024) {
            int gjv = gj - 1024;
            reinterpret_cast<ushort*>(Out2)[(((size_t)(bb * CH + (gjv >> 6)) * CDK + (gjv & 63)) * CT + t)] = f2bf(v);
          } else {
            reinterpret_cast<ushort*>(Out)[(((size_t)(bb * CH + (gj >> 6)) * CT + t) * CDK + (gj & 63))] = f2bf(v);
          }
        }
      }
    }
}

// ---------------- fused attention (round-6: staged LDS, 8 waves / 128 q-rows, 2-pass) ----------
__global__ __launch_bounds__(512, 2)
void attn_kernel(const ushort* __restrict__ Qb, const ushort* __restrict__ Kb,
                 const ushort* __restrict__ Vt, const int* __restrict__ mask,
                 const uint* __restrict__ flags,
                 float* __restrict__ attn_out, ushort* __restrict__ oh)
{
  constexpr int KB = 64, LDK = 72;
  __shared__ __align__(16) ushort Ks[KB * LDK];
  __shared__ __align__(16) ushort Vs[CDK * LDK];
  __shared__ __align__(16) ushort Ps[8][16 * LDK];

  const int tid = threadIdx.x, wid = tid >> 6, lane = tid & 63;
  const int bh = blockIdx.y, b = bh >> 4, h = bh & 15;
  const int q0 = blockIdx.x * 128 + wid * 16;
  const int rsel = lane & 15, grp = lane >> 4, ksel = grp * 8;
  const int srow = tid >> 3, scol = (tid & 7) * 8;
  const uint* fl = flags + (b << 10) + ((q0 >> 6) << 5);

  short8 qa0, qa1;
  {
    const ushort* qrow = Qb + ((size_t)bh * CT + q0 + rsel) * CDK;
    qa0 = *reinterpret_cast<const short8*>(qrow + ksel);
    qa1 = *reinterpret_cast<const short8*>(qrow + 32 + ksel);
  }

  float l_part[4] = {0.f, 0.f, 0.f, 0.f};
  const int* mrow = mask + (size_t)b * CT * CT;

  for (int k0 = 0; k0 < CT; k0 += KB) {
    __syncthreads();
    *reinterpret_cast<short8*>(&Ks[srow * LDK + scol]) =
        *reinterpret_cast<const short8*>(&Kb[((size_t)bh * CT + k0 + srow) * CDK + scol]);
    __syncthreads();
    const uint f = fl[k0 >> 6];
    for (int ni = 0; ni < 4; ++ni) {
      f32x4 z = {0.f, 0.f, 0.f, 0.f};
      short8 kb0 = *reinterpret_cast<short8*>(&Ks[(ni * 16 + rsel) * LDK + ksel]);
      short8 kb1 = *reinterpret_cast<short8*>(&Ks[(ni * 16 + rsel) * LDK + 32 + ksel]);
      z = __builtin_amdgcn_mfma_f32_16x16x32_bf16(qa0, kb0, z, 0, 0, 0);
      z = __builtin_amdgcn_mfma_f32_16x16x32_bf16(qa1, kb1, z, 0, 0, 0);
      if (f) {
        for (int r = 0; r < 4; ++r) l_part[r] += exp2f(z[r]);
      } else {
        int kk = k0 + ni * 16 + rsel;
        for (int r = 0; r < 4; ++r) {
          int q = q0 + grp * 4 + r;
          l_part[r] += mrow[(size_t)q * CT + kk] ? exp2f(z[r]) : 0.f;
        }
      }
    }
  }
  for (int off = 1; off < 16; off <<= 1)
    for (int r = 0; r < 4; ++r) l_part[r] += __shfl_xor(l_part[r], off, 64);
  float inv_l[4];
  for (int r = 0; r < 4; ++r) inv_l[r] = 1.f / l_part[r];

  f32x4 oacc[4];
  for (int nd = 0; nd < 4; ++nd) oacc[nd] = f32x4{0.f, 0.f, 0.f, 0.f};
  float* arow = attn_out + (size_t)bh * CT * CT;
  ushort* pw = &Ps[wid][0];

  for (int k0 = 0; k0 < CT; k0 += KB) {
    __syncthreads();
    *reinterpret_cast<short8*>(&Ks[srow * LDK + scol]) =
        *reinterpret_cast<const short8*>(&Kb[((size_t)bh * CT + k0 + srow) * CDK + scol]);
    *reinterpret_cast<short8*>(&Vs[srow * LDK + scol]) =
        *reinterpret_cast<const short8*>(&Vt[((size_t)bh * CDK + srow) * CT + k0 + scol]);
    __syncthreads();
    const uint f = fl[k0 >> 6];
    for (int ni = 0; ni < 4; ++ni) {
      f32x4 z = {0.f, 0.f, 0.f, 0.f};
      short8 kb0 = *reinterpret_cast<short8*>(&Ks[(ni * 16 + rsel) * LDK + ksel]);
      short8 kb1 = *reinterpret_cast<short8*>(&Ks[(ni * 16 + rsel) * LDK + 32 + ksel]);
      z = __builtin_amdgcn_mfma_f32_16x16x32_bf16(qa0, kb0, z, 0, 0, 0);
      z = __builtin_amdgcn_mfma_f32_16x16x32_bf16(qa1, kb1, z, 0, 0, 0);
      int kk = k0 + ni * 16 + rsel;
      for (int r = 0; r < 4; ++r) {
        int q = q0 + grp * 4 + r;
        float p;
        if (f) p = exp2f(z[r]);
        else   p = mrow[(size_t)q * CT + kk] ? exp2f(z[r]) : 0.f;
        arow[(size_t)q * CT + kk] = p * inv_l[r];
        pw[(grp * 4 + r) * LDK + ni * 16 + rsel] = f2bf(p);
      }
    }
    short8 pa0 = *reinterpret_cast<short8*>(&pw[rsel * LDK + ksel]);
    short8 pa1 = *reinterpret_cast<short8*>(&pw[rsel * LDK + 32 + ksel]);
    for (int nd = 0; nd < 4; ++nd) {
      short8 vb0 = *reinterpret_cast<short8*>(&Vs[(nd * 16 + rsel) * LDK + ksel]);
      short8 vb1 = *reinterpret_cast<short8*>(&Vs[(nd * 16 + rsel) * LDK + 32 + ksel]);
      oacc[nd] = __builtin_amdgcn_mfma_f32_16x16x32_bf16(pa0, vb0, oacc[nd], 0, 0, 0);
      oacc[nd] = __builtin_amdgcn_mfma_f32_16x16x32_bf16(pa1, vb1, oacc[nd], 0, 0, 0);
    }
  }

  for (int nd = 0; nd < 4; ++nd)
    for (int r = 0; r < 4; ++r) {
      int q = q0 + grp * 4 + r, d = nd * 16 + rsel;
      oh[((size_t)b * CT + q) * CD + h * CDK + d] = f2bf(oacc[nd][r] * inv_l[r]);
    }
}

// ---------------- launcher ----------------
extern "C" void kernel_launch(void* const* d_in, const int* in_sizes, int n_in,
                              void* d_out, int out_size, void* d_ws, size_t ws_size,
                              hipStream_t stream)
{
  const float* x_q  = (const float*)d_in[0];
  const float* x_kv = (const float*)d_in[1];
  const int*   mask = (const int*)d_in[2];
  const float* Wq = (const float*)d_in[3];
  const float* bq = (const float*)d_in[4];
  const float* Wk = (const float*)d_in[5];
  const float* bk = (const float*)d_in[6];
  const float* Wv = (const float*)d_in[7];
  const float* bv = (const float*)d_in[8];
  const float* Wo = (const float*)d_in[9];
  const float* bo = (const float*)d_in[10];

  float* out  = (float*)d_out;
  float* attn = out + (size_t)CB * CT * CD;

  char* w = (char*)d_ws;
  auto alloc = [&](size_t bytes) { char* p = w; w += (bytes + 255) & ~(size_t)255; return p; };
  ushort* xq_bf  = (ushort*)alloc((size_t)CM * CD * 2);
  ushort* xkv_bf = (ushort*)alloc((size_t)CM * CD * 2);
  ushort* Wq_bf  = (ushort*)alloc((size_t)CD * CD * 2);
  ushort* Wk_bf  = (ushort*)alloc((size_t)CD * CD * 2); // NOTE: Wk_bf and Wv_bf are contiguous (2MB each, 256-aligned)
  ushort* Wv_bf  = (ushort*)alloc((size_t)CD * CD * 2);
  ushort* Wo_bf  = (ushort*)alloc((size_t)CD * CD * 2);
  ushort* Q_bf   = (ushort*)alloc((size_t)CM * CD * 2);
  ushort* K_bf   = (ushort*)alloc((size_t)CM * CD * 2);
  ushort* Vt_bf  = (ushort*)alloc((size_t)CM * CD * 2);
  ushort* oh_bf  = (ushort*)alloc((size_t)CM * CD * 2);
  uint*   mflags = (uint*)alloc(2048 * sizeof(uint));

  {
    const int nx = CM * CD, nw = CD * CD;
    const int total_quads = (2 * nx + 4 * nw) / 4;
    const int blocks = (total_quads + 255) / 256;
    hipLaunchKernelGGL(cvt_all_kernel, dim3(blocks), dim3(256), 0, stream,
                       x_q, xq_bf, nx, x_kv, xkv_bf, nx,
                       Wq, Wq_bf, nw, Wk, Wk_bf, nw,
                       Wv, Wv_bf, nw, Wo, Wo_bf, nw);
  }

  hipLaunchKernelGGL(mask_flags_kernel, dim3(2048), dim3(256), 0, stream, mask, mflags);

  // Q proj (scale folds 1/sqrt(DK)*log2e), grid (N/64, M/128)
  hipLaunchKernelGGL(gemm_nt_kernel, dim3(CD / 64, CM / 128), dim3(256), 0, stream,
                     xq_bf, Wq_bf, bq, bq, (void*)Q_bf, nullptr, CM, CD, CD, 0, 0.125f * LOG2E);
  // K+V merged proj: B = [Wk;Wv] (contiguous), N=2048, mode 3
  hipLaunchKernelGGL(gemm_nt_kernel, dim3(2 * CD / 64, CM / 128), dim3(256), 0, stream,
                     xkv_bf, Wk_bf, bk, bv, (void*)K_bf, (void*)Vt_bf, CM, 2 * CD, CD, 3, 1.0f);

  hipLaunchKernelGGL(attn_kernel, dim3(CT / 128, CB * CH), dim3(512), 0, stream,
                     Q_bf, K_bf, Vt_bf, mask, mflags, attn, oh_bf);

  hipLaunchKernelGGL(gemm_nt_kernel, dim3(CD / 64, CM / 128), dim3(256), 0, stream,
                     oh_bf, Wo_bf, bo, bo, d_out, nullptr, CM, CD, CD, 2, 1.0f);
}

// Round 9
// 330.666 us; speedup vs baseline: 1.1529x; 1.0025x over previous
//
#include <hip/hip_runtime.h>
#include <hip/hip_bf16.h>

#define DEVINL __device__ __forceinline__

typedef __attribute__((ext_vector_type(4))) float f32x4;
typedef __attribute__((ext_vector_type(8))) short short8;
typedef __attribute__((ext_vector_type(4))) short short4v;

constexpr int CB = 2, CT = 2048, CD = 1024, CH = 16, CDK = 64;
constexpr int CM = CB * CT; // 4096 rows
constexpr float LOG2E = 1.44269504088896340736f;

DEVINL ushort f2bf(float f) {
  __hip_bfloat16 h = __float2bfloat16(f); // RNE
  ushort u; __builtin_memcpy(&u, &h, 2); return u;
}

DEVINL void gl2lds16(const ushort* g, ushort* ldsbase) {
  __builtin_amdgcn_global_load_lds(
      (const __attribute__((address_space(1))) void*)g,
      (__attribute__((address_space(3))) void*)ldsbase, 16, 0, 0);
}

// ---------------- fused f32 -> bf16 convert (all 6 tensors, one launch) ----------------
__global__ void cvt_all_kernel(const float* __restrict__ s0, ushort* __restrict__ d0, int n0,
                               const float* __restrict__ s1, ushort* __restrict__ d1, int n1,
                               const float* __restrict__ s2, ushort* __restrict__ d2, int n2,
                               const float* __restrict__ s3, ushort* __restrict__ d3, int n3,
                               const float* __restrict__ s4, ushort* __restrict__ d4, int n4,
                               const float* __restrict__ s5, ushort* __restrict__ d5, int n5)
{
  int i = (blockIdx.x * blockDim.x + threadIdx.x) * 4;
  const float* s; ushort* d;
  if (i < n0) { s = s0; d = d0; }
  else if ((i -= n0) < n1) { s = s1; d = d1; }
  else if ((i -= n1) < n2) { s = s2; d = d2; }
  else if ((i -= n2) < n3) { s = s3; d = d3; }
  else if ((i -= n3) < n4) { s = s4; d = d4; }
  else if ((i -= n4) < n5) { s = s5; d = d5; }
  else return;
  float4 v = *reinterpret_cast<const float4*>(s + i);
  ushort4 o;
  o.x = f2bf(v.x); o.y = f2bf(v.y); o.z = f2bf(v.z); o.w = f2bf(v.w);
  *reinterpret_cast<ushort4*>(d + i) = o;
}

// ---------------- mask -> per-64x64-tile all-valid flags ----------------
__global__ void mask_flags_kernel(const int* __restrict__ mask, uint* __restrict__ flags) {
  const int tile = blockIdx.x;              // 2048 tiles
  const int b = tile >> 10, qb = (tile >> 5) & 31, kb = tile & 31;
  const int* base = mask + ((size_t)b * CT + qb * 64) * CT + kb * 64;
  const int r = threadIdx.x >> 2, c0 = (threadIdx.x & 3) * 16;
  int ok = 1;
  for (int j = 0; j < 4; ++j) {
    int4 v = *reinterpret_cast<const int4*>(base + (size_t)r * CT + c0 + j * 4);
    ok &= (v.x != 0) & (v.y != 0) & (v.z != 0) & (v.w != 0);
  }
  __shared__ int red[4];
  unsigned long long bal = __ballot(ok);
  if ((threadIdx.x & 63) == 0) red[threadIdx.x >> 6] = (bal == ~0ull);
  __syncthreads();
  if (threadIdx.x == 0) flags[tile] = (uint)(red[0] & red[1] & red[2] & red[3]);
}

// ---------------- NT GEMM, 2-phase double-buffered global_load_lds (round-8) ----------------
__global__ __launch_bounds__(256, 2)
void gemm_nt_kernel(const ushort* __restrict__ A, const ushort* __restrict__ Bm,
                    const float* __restrict__ bias1, const float* __restrict__ bias2,
                    void* __restrict__ Out, void* __restrict__ Out2,
                    int M, int N, int K, int mode, float scale)
{
  constexpr int BM = 128, BN = 64, BK = 32;
  __shared__ __align__(16) ushort As[2][BM * BK];
  __shared__ __align__(16) ushort Bs[2][BN * BK];
  const int tid = threadIdx.x;
  const int lane = tid & 63, wid = tid >> 6;
  const int wr = wid >> 1, wc = wid & 1;
  const int bm0 = blockIdx.y * BM, bn0 = blockIdx.x * BN;
  const int rsel = lane & 15, ksel = (lane >> 4) * 8;
  const int srow = lane >> 2, sc8 = (lane & 3) * 8;

  f32x4 acc[4][2];
  for (int i = 0; i < 4; ++i) for (int j = 0; j < 2; ++j) acc[i][j] = f32x4{0.f, 0.f, 0.f, 0.f};

  auto stage = [&](int bu, int k0) {
    const int ra0 = wid * 32;
    gl2lds16(&A[(size_t)(bm0 + ra0 + srow) * K + k0 + sc8],      &As[bu][ra0 * BK]);
    gl2lds16(&A[(size_t)(bm0 + ra0 + 16 + srow) * K + k0 + sc8], &As[bu][(ra0 + 16) * BK]);
    const int rb0 = wid * 16;
    gl2lds16(&Bm[(size_t)(bn0 + rb0 + srow) * K + k0 + sc8],     &Bs[bu][rb0 * BK]);
  };

  stage(0, 0);
  __syncthreads();
  const int NKT = K / BK;
  int bu = 0;
  for (int kt = 0; kt < NKT; ++kt) {
    if (kt + 1 < NKT) stage(bu ^ 1, (kt + 1) * BK);
    short8 af[4], bfr[2];
    for (int mi = 0; mi < 4; ++mi)
      af[mi] = *reinterpret_cast<short8*>(&As[bu][(wr * 64 + mi * 16 + rsel) * BK + ksel]);
    for (int ni = 0; ni < 2; ++ni)
      bfr[ni] = *reinterpret_cast<short8*>(&Bs[bu][(wc * 32 + ni * 16 + rsel) * BK + ksel]);
    for (int mi = 0; mi < 4; ++mi)
      for (int ni = 0; ni < 2; ++ni)
        acc[mi][ni] = __builtin_amdgcn_mfma_f32_16x16x32_bf16(af[mi], bfr[ni], acc[mi][ni], 0, 0, 0);
    if (kt + 1 < NKT) { __syncthreads(); bu ^= 1; }
  }

  const int r0 = (lane >> 4) * 4;
  for (int mi = 0; mi < 4; ++mi)
    for (int ni = 0; ni < 2; ++ni) {
      int gj = bn0 + wc * 32 + ni * 16 + rsel;
      float bv = (mode == 3 && gj >= 1024) ? bias2[gj - 1024] : bias1[gj];
      for (int r = 0; r < 4; ++r) {
        int gi = bm0 + wr * 64 + mi * 16 + r0 + r;
        float v = (acc[mi][ni][r] + bv) * scale;
        if (mode == 2) {
          reinterpret_cast<float*>(Out)[(size_t)gi * N + gj] = v;
        } else {
          int bb = gi >> 11, t = gi & (CT - 1);
          if (mode == 3 && gj >= 1024) {
            int gjv = gj - 1024;
            reinterpret_cast<ushort*>(Out2)[(((size_t)(bb * CH + (gjv >> 6)) * CDK + (gjv & 63)) * CT + t)] = f2bf(v);
          } else {
            reinterpret_cast<ushort*>(Out)[(((size_t)(bb * CH + (gj >> 6)) * CT + t) * CDK + (gj & 63))] = f2bf(v);
          }
        }
      }
    }
}

// ---------------- fused attention: swapped-QK + gl2lds dbuf staging ----------------
// grid: (T/128, B*H), 8 waves. Qb has 0.125*log2e folded in. Kb:(B,H,T,DK). Vt:(B,H,DK,T).
// QK^T computed as mfma(K_frag, Q_frag): D row = k-seq (grp*4+r contiguous), col = q (rsel)
// -> float4 attn stores and packed short4 P writes.
// K/V tiles staged via global_load_lds into LINEAR [64][64] LDS with XOR-swizzled source:
//   LDS chunk(row, slot) holds logical col-chunk (slot ^ (row&7));
//   read fragment (row, chunk c) at elem row*64 + ((c ^ (row&7))*8) -> ~2-way banks (free).
__global__ __launch_bounds__(512, 2)
void attn_kernel(const ushort* __restrict__ Qb, const ushort* __restrict__ Kb,
                 const ushort* __restrict__ Vt, const int* __restrict__ mask,
                 const uint* __restrict__ flags,
                 float* __restrict__ attn_out, ushort* __restrict__ oh)
{
  constexpr int LDP = 72; // P rows 144B -> 16B-aligned short8 reads
  __shared__ __align__(16) ushort Ks[2][64 * 64];
  __shared__ __align__(16) ushort Vs[2][64 * 64];
  __shared__ __align__(16) ushort Ps[8][16 * LDP];

  const int tid = threadIdx.x, wid = tid >> 6, lane = tid & 63;
  const int bh = blockIdx.y, b = bh >> 4, h = bh & 15;
  const int q0 = blockIdx.x * 128 + wid * 16;
  const int rsel = lane & 15, grp = lane >> 4, ksel = grp * 8;
  const int swz = rsel & 7;
  const uint* fl = flags + (b << 10) + ((q0 >> 6) << 5);
  const ushort* kpan = Kb + (size_t)bh * CT * CDK;
  const ushort* vpan = Vt + (size_t)bh * CDK * CT;

  // staging: 512 threads cover 64 rows x 8 col-chunks; source pre-swizzled (rule 21)
  const int strow = tid >> 3, stc = (tid & 7) ^ (strow & 7);

  auto stageK = [&](int bu, int k0) {
    gl2lds16(&kpan[(size_t)(k0 + strow) * CDK + stc * 8], &Ks[bu][(size_t)wid * 512]);
  };
  auto stageV = [&](int bu, int k0) {
    gl2lds16(&vpan[(size_t)strow * CT + k0 + stc * 8], &Vs[bu][(size_t)wid * 512]);
  };

  // Q fragments (B-operand): lane holds Q[q0+rsel][dk = grp*8..+8] halves
  short8 qa0, qa1;
  {
    const ushort* qrow = Qb + ((size_t)bh * CT + q0 + rsel) * CDK;
    qa0 = *reinterpret_cast<const short8*>(qrow + ksel);
    qa1 = *reinterpret_cast<const short8*>(qrow + 32 + ksel);
  }

  const int* mrow = mask + (size_t)b * CT * CT;
  const int qme = q0 + rsel; // this lane's q row (for l, attn stores, mask)

  // ---- pass 1: l[q] = sum_k exp2(S) ; scalar per lane, dbuf K staging ----
  float l_lane = 0.f;
  stageK(0, 0);
  __syncthreads();
  int bu = 0;
  for (int kt = 0; kt < 32; ++kt) {
    const int k0 = kt * 64;
    if (kt + 1 < 32) stageK(bu ^ 1, k0 + 64);
    const uint f = fl[kt];
    for (int ni = 0; ni < 4; ++ni) {
      const int krow = ni * 16 + rsel;
      short8 kb0 = *reinterpret_cast<short8*>(&Ks[bu][krow * 64 + ((grp    ) ^ swz) * 8]);
      short8 kb1 = *reinterpret_cast<short8*>(&Ks[bu][krow * 64 + ((grp + 4) ^ swz) * 8]);
      f32x4 z = {0.f, 0.f, 0.f, 0.f};
      z = __builtin_amdgcn_mfma_f32_16x16x32_bf16(kb0, qa0, z, 0, 0, 0);
      z = __builtin_amdgcn_mfma_f32_16x16x32_bf16(kb1, qa1, z, 0, 0, 0);
      if (f) {
        l_lane += exp2f(z[0]) + exp2f(z[1]) + exp2f(z[2]) + exp2f(z[3]);
      } else {
        const int kb_ = k0 + ni * 16 + grp * 4;
        for (int r = 0; r < 4; ++r)
          l_lane += mrow[(size_t)qme * CT + kb_ + r] ? exp2f(z[r]) : 0.f;
      }
    }
    __syncthreads();
    bu ^= 1;
  }
  // reduce over the 4 grp-lanes sharing this rsel
  l_lane += __shfl_xor(l_lane, 16, 64);
  l_lane += __shfl_xor(l_lane, 32, 64);
  const float inv_l = 1.f / l_lane;

  // ---- pass 2: recompute, write attn (float4), P->LDS (short4), PV ----
  f32x4 oacc[4];
  for (int nd = 0; nd < 4; ++nd) oacc[nd] = f32x4{0.f, 0.f, 0.f, 0.f};
  float* aq = attn_out + (size_t)bh * CT * CT + (size_t)qme * CT;
  ushort* pw = &Ps[wid][0];

  stageK(0, 0);
  stageV(0, 0);
  __syncthreads();
  bu = 0;
  for (int kt = 0; kt < 32; ++kt) {
    const int k0 = kt * 64;
    if (kt + 1 < 32) { stageK(bu ^ 1, k0 + 64); stageV(bu ^ 1, k0 + 64); }
    const uint f = fl[kt];
    for (int ni = 0; ni < 4; ++ni) {
      const int krow = ni * 16 + rsel;
      short8 kb0 = *reinterpret_cast<short8*>(&Ks[bu][krow * 64 + ((grp    ) ^ swz) * 8]);
      short8 kb1 = *reinterpret_cast<short8*>(&Ks[bu][krow * 64 + ((grp + 4) ^ swz) * 8]);
      f32x4 z = {0.f, 0.f, 0.f, 0.f};
      z = __builtin_amdgcn_mfma_f32_16x16x32_bf16(kb0, qa0, z, 0, 0, 0);
      z = __builtin_amdgcn_mfma_f32_16x16x32_bf16(kb1, qa1, z, 0, 0, 0);
      const int kb_ = k0 + ni * 16 + grp * 4; // 4 consecutive k in this lane
      float p0, p1, p2, p3;
      if (f) {
        p0 = exp2f(z[0]); p1 = exp2f(z[1]); p2 = exp2f(z[2]); p3 = exp2f(z[3]);
      } else {
        const size_t mb = (size_t)qme * CT + kb_;
        p0 = mrow[mb + 0] ? exp2f(z[0]) : 0.f;
        p1 = mrow[mb + 1] ? exp2f(z[1]) : 0.f;
        p2 = mrow[mb + 2] ? exp2f(z[2]) : 0.f;
        p3 = mrow[mb + 3] ? exp2f(z[3]) : 0.f;
      }
      float4 st = make_float4(p0 * inv_l, p1 * inv_l, p2 * inv_l, p3 * inv_l);
      *reinterpret_cast<float4*>(aq + kb_) = st;
      short4v pk = {(short)f2bf(p0), (short)f2bf(p1), (short)f2bf(p2), (short)f2bf(p3)};
      *reinterpret_cast<short4v*>(&pw[rsel * LDP + ni * 16 + grp * 4]) = pk;
    }
    // re-fragment P as A-operand: lane reads P[q=rsel][k = grp*8..+8] per 32-k half
    short8 pa0 = *reinterpret_cast<short8*>(&pw[rsel * LDP + ksel]);
    short8 pa1 = *reinterpret_cast<short8*>(&pw[rsel * LDP + 32 + ksel]);
    for (int nd = 0; nd < 4; ++nd) {
      const int vrow = nd * 16 + rsel;
      short8 vb0 = *reinterpret_cast<short8*>(&Vs[bu][vrow * 64 + ((grp    ) ^ swz) * 8]);
      short8 vb1 = *reinterpret_cast<short8*>(&Vs[bu][vrow * 64 + ((grp + 4) ^ swz) * 8]);
      oacc[nd] = __builtin_amdgcn_mfma_f32_16x16x32_bf16(pa0, vb0, oacc[nd], 0, 0, 0);
      oacc[nd] = __builtin_amdgcn_mfma_f32_16x16x32_bf16(pa1, vb1, oacc[nd], 0, 0, 0);
    }
    __syncthreads();
    bu ^= 1;
  }

  // oh write: D row = q(grp*4+r), col = d(nd*16+rsel); fetch inv_l for those q via shfl
  float invl_o[4];
  for (int r = 0; r < 4; ++r) invl_o[r] = __shfl(inv_l, grp * 4 + r, 16);
  for (int nd = 0; nd < 4; ++nd)
    for (int r = 0; r < 4; ++r) {
      int q = q0 + grp * 4 + r, d = nd * 16 + rsel;
      oh[((size_t)b * CT + q) * CD + h * CDK + d] = f2bf(oacc[nd][r] * invl_o[r]);
    }
}

// ---------------- launcher ----------------
extern "C" void kernel_launch(void* const* d_in, const int* in_sizes, int n_in,
                              void* d_out, int out_size, void* d_ws, size_t ws_size,
                              hipStream_t stream)
{
  const float* x_q  = (const float*)d_in[0];
  const float* x_kv = (const float*)d_in[1];
  const int*   mask = (const int*)d_in[2];
  const float* Wq = (const float*)d_in[3];
  const float* bq = (const float*)d_in[4];
  const float* Wk = (const float*)d_in[5];
  const float* bk = (const float*)d_in[6];
  const float* Wv = (const float*)d_in[7];
  const float* bv = (const float*)d_in[8];
  const float* Wo = (const float*)d_in[9];
  const float* bo = (const float*)d_in[10];

  float* out  = (float*)d_out;
  float* attn = out + (size_t)CB * CT * CD;

  char* w = (char*)d_ws;
  auto alloc = [&](size_t bytes) { char* p = w; w += (bytes + 255) & ~(size_t)255; return p; };
  ushort* xq_bf  = (ushort*)alloc((size_t)CM * CD * 2);
  ushort* xkv_bf = (ushort*)alloc((size_t)CM * CD * 2);
  ushort* Wq_bf  = (ushort*)alloc((size_t)CD * CD * 2);
  ushort* Wk_bf  = (ushort*)alloc((size_t)CD * CD * 2); // Wk_bf/Wv_bf contiguous (2MB each, 256-aligned)
  ushort* Wv_bf  = (ushort*)alloc((size_t)CD * CD * 2);
  ushort* Wo_bf  = (ushort*)alloc((size_t)CD * CD * 2);
  ushort* Q_bf   = (ushort*)alloc((size_t)CM * CD * 2);
  ushort* K_bf   = (ushort*)alloc((size_t)CM * CD * 2);
  ushort* Vt_bf  = (ushort*)alloc((size_t)CM * CD * 2);
  ushort* oh_bf  = (ushort*)alloc((size_t)CM * CD * 2);
  uint*   mflags = (uint*)alloc(2048 * sizeof(uint));

  {
    const int nx = CM * CD, nw = CD * CD;
    const int total_quads = (2 * nx + 4 * nw) / 4;
    const int blocks = (total_quads + 255) / 256;
    hipLaunchKernelGGL(cvt_all_kernel, dim3(blocks), dim3(256), 0, stream,
                       x_q, xq_bf, nx, x_kv, xkv_bf, nx,
                       Wq, Wq_bf, nw, Wk, Wk_bf, nw,
                       Wv, Wv_bf, nw, Wo, Wo_bf, nw);
  }

  hipLaunchKernelGGL(mask_flags_kernel, dim3(2048), dim3(256), 0, stream, mask, mflags);

  hipLaunchKernelGGL(gemm_nt_kernel, dim3(CD / 64, CM / 128), dim3(256), 0, stream,
                     xq_bf, Wq_bf, bq, bq, (void*)Q_bf, nullptr, CM, CD, CD, 0, 0.125f * LOG2E);
  hipLaunchKernelGGL(gemm_nt_kernel, dim3(2 * CD / 64, CM / 128), dim3(256), 0, stream,
                     xkv_bf, Wk_bf, bk, bv, (void*)K_bf, (void*)Vt_bf, CM, 2 * CD, CD, 3, 1.0f);

  hipLaunchKernelGGL(attn_kernel, dim3(CT / 128, CB * CH), dim3(512), 0, stream,
                     Q_bf, K_bf, Vt_bf, mask, mflags, attn, oh_bf);

  hipLaunchKernelGGL(gemm_nt_kernel, dim3(CD / 64, CM / 128), dim3(256), 0, stream,
                     oh_bf, Wo_bf, bo, bo, d_out, nullptr, CM, CD, CD, 2, 1.0f);
}

// Round 11
// 283.645 us; speedup vs baseline: 1.3441x; 1.1658x over previous
//
#include <hip/hip_runtime.h>
#include <hip/hip_bf16.h>

#define DEVINL __device__ __forceinline__

typedef __attribute__((ext_vector_type(4))) float f32x4;
typedef __attribute__((ext_vector_type(8))) short short8;

constexpr int CB = 2, CT = 2048, CD = 1024, CH = 16, CDK = 64;
constexpr int CM = CB * CT; // 4096 rows
constexpr float LOG2E = 1.44269504088896340736f;

DEVINL ushort f2bf(float f) {
  __hip_bfloat16 h = __float2bfloat16(f); // RNE
  ushort u; __builtin_memcpy(&u, &h, 2); return u;
}

DEVINL void gl2lds16(const ushort* g, ushort* ldsbase) {
  __builtin_amdgcn_global_load_lds(
      (const __attribute__((address_space(1))) void*)g,
      (__attribute__((address_space(3))) void*)ldsbase, 16, 0, 0);
}

// ---------------- fused f32 -> bf16 convert (all 6 tensors, one launch) ----------------
__global__ void cvt_all_kernel(const float* __restrict__ s0, ushort* __restrict__ d0, int n0,
                               const float* __restrict__ s1, ushort* __restrict__ d1, int n1,
                               const float* __restrict__ s2, ushort* __restrict__ d2, int n2,
                               const float* __restrict__ s3, ushort* __restrict__ d3, int n3,
                               const float* __restrict__ s4, ushort* __restrict__ d4, int n4,
                               const float* __restrict__ s5, ushort* __restrict__ d5, int n5)
{
  int i = (blockIdx.x * blockDim.x + threadIdx.x) * 4;
  const float* s; ushort* d;
  if (i < n0) { s = s0; d = d0; }
  else if ((i -= n0) < n1) { s = s1; d = d1; }
  else if ((i -= n1) < n2) { s = s2; d = d2; }
  else if ((i -= n2) < n3) { s = s3; d = d3; }
  else if ((i -= n3) < n4) { s = s4; d = d4; }
  else if ((i -= n4) < n5) { s = s5; d = d5; }
  else return;
  float4 v = *reinterpret_cast<const float4*>(s + i);
  ushort4 o;
  o.x = f2bf(v.x); o.y = f2bf(v.y); o.z = f2bf(v.z); o.w = f2bf(v.w);
  *reinterpret_cast<ushort4*>(d + i) = o;
}

// ---------------- mask -> per-64x64-tile all-valid flags ----------------
__global__ void mask_flags_kernel(const int* __restrict__ mask, uint* __restrict__ flags) {
  const int tile = blockIdx.x;              // 2048 tiles
  const int b = tile >> 10, qb = (tile >> 5) & 31, kb = tile & 31;
  const int* base = mask + ((size_t)b * CT + qb * 64) * CT + kb * 64;
  const int r = threadIdx.x >> 2, c0 = (threadIdx.x & 3) * 16;
  int ok = 1;
  for (int j = 0; j < 4; ++j) {
    int4 v = *reinterpret_cast<const int4*>(base + (size_t)r * CT + c0 + j * 4);
    ok &= (v.x != 0) & (v.y != 0) & (v.z != 0) & (v.w != 0);
  }
  __shared__ int red[4];
  unsigned long long bal = __ballot(ok);
  if ((threadIdx.x & 63) == 0) red[threadIdx.x >> 6] = (bal == ~0ull);
  __syncthreads();
  if (threadIdx.x == 0) flags[tile] = (uint)(red[0] & red[1] & red[2] & red[3]);
}

// ---------------- NT GEMM, 2-phase double-buffered global_load_lds (round-8) ----------------
__global__ __launch_bounds__(256, 2)
void gemm_nt_kernel(const ushort* __restrict__ A, const ushort* __restrict__ Bm,
                    const float* __restrict__ bias1, const float* __restrict__ bias2,
                    void* __restrict__ Out, void* __restrict__ Out2,
                    int M, int N, int K, int mode, float scale)
{
  constexpr int BM = 128, BN = 64, BK = 32;
  __shared__ __align__(16) ushort As[2][BM * BK];
  __shared__ __align__(16) ushort Bs[2][BN * BK];
  const int tid = threadIdx.x;
  const int lane = tid & 63, wid = tid >> 6;
  const int wr = wid >> 1, wc = wid & 1;
  const int bm0 = blockIdx.y * BM, bn0 = blockIdx.x * BN;
  const int rsel = lane & 15, ksel = (lane >> 4) * 8;
  const int srow = lane >> 2, sc8 = (lane & 3) * 8;

  f32x4 acc[4][2];
  for (int i = 0; i < 4; ++i) for (int j = 0; j < 2; ++j) acc[i][j] = f32x4{0.f, 0.f, 0.f, 0.f};

  auto stage = [&](int bu, int k0) {
    const int ra0 = wid * 32;
    gl2lds16(&A[(size_t)(bm0 + ra0 + srow) * K + k0 + sc8],      &As[bu][ra0 * BK]);
    gl2lds16(&A[(size_t)(bm0 + ra0 + 16 + srow) * K + k0 + sc8], &As[bu][(ra0 + 16) * BK]);
    const int rb0 = wid * 16;
    gl2lds16(&Bm[(size_t)(bn0 + rb0 + srow) * K + k0 + sc8],     &Bs[bu][rb0 * BK]);
  };

  stage(0, 0);
  __syncthreads();
  const int NKT = K / BK;
  int bu = 0;
  for (int kt = 0; kt < NKT; ++kt) {
    if (kt + 1 < NKT) stage(bu ^ 1, (kt + 1) * BK);
    short8 af[4], bfr[2];
    for (int mi = 0; mi < 4; ++mi)
      af[mi] = *reinterpret_cast<short8*>(&As[bu][(wr * 64 + mi * 16 + rsel) * BK + ksel]);
    for (int ni = 0; ni < 2; ++ni)
      bfr[ni] = *reinterpret_cast<short8*>(&Bs[bu][(wc * 32 + ni * 16 + rsel) * BK + ksel]);
    for (int mi = 0; mi < 4; ++mi)
      for (int ni = 0; ni < 2; ++ni)
        acc[mi][ni] = __builtin_amdgcn_mfma_f32_16x16x32_bf16(af[mi], bfr[ni], acc[mi][ni], 0, 0, 0);
    if (kt + 1 < NKT) { __syncthreads(); bu ^= 1; }
  }

  const int r0 = (lane >> 4) * 4;
  for (int mi = 0; mi < 4; ++mi)
    for (int ni = 0; ni < 2; ++ni) {
      int gj = bn0 + wc * 32 + ni * 16 + rsel;
      float bv = (mode == 3 && gj >= 1024) ? bias2[gj - 1024] : bias1[gj];
      for (int r = 0; r < 4; ++r) {
        int gi = bm0 + wr * 64 + mi * 16 + r0 + r;
        float v = (acc[mi][ni][r] + bv) * scale;
        if (mode == 2) {
          reinterpret_cast<float*>(Out)[(size_t)gi * N + gj] = v;
        } else {
          int bb = gi >> 11, t = gi & (CT - 1);
          if (mode == 3 && gj >= 1024) {
            int gjv = gj - 1024;
            reinterpret_cast<ushort*>(Out2)[(((size_t)(bb * CH + (gjv >> 6)) * CDK + (gjv & 63)) * CT + t)] = f2bf(v);
          } else {
            reinterpret_cast<ushort*>(Out)[(((size_t)(bb * CH + (gj >> 6)) * CT + t) * CDK + (gj & 63))] = f2bf(v);
          }
        }
      }
    }
}

// ---------------- fused attention: swapped-QK, coalesced NT attn stores ----------------
// grid: (T/128, B*H), 8 waves. Qb has 0.125*log2e folded in. Kb:(B,H,T,DK). Vt:(B,H,DK,T).
// QK^T computed as mfma(K_frag, Q_frag): lane (rsel,grp) holds S[q=rsel][k=kb_..kb_+4].
// P is pre-scaled by 1/l via exp2(z - log2(l)) and staged per-wave in XOR-swizzled f32 LDS;
// attn stores are cooperative flushes: 256B contiguous per q-row per instruction, nontemporal.
__global__ __launch_bounds__(512, 2)
void attn_kernel(const ushort* __restrict__ Qb, const ushort* __restrict__ Kb,
                 const ushort* __restrict__ Vt, const int* __restrict__ mask,
                 const uint* __restrict__ flags,
                 float* __restrict__ attn_out, ushort* __restrict__ oh)
{
  __shared__ __align__(16) ushort Ks[2][64 * 64];
  __shared__ __align__(16) ushort Vs[2][64 * 64];
  __shared__ __align__(16) float  Pf[8][16 * 64]; // per-wave 16x64 f32, float4-chunk XOR swizzle

  const int tid = threadIdx.x, wid = tid >> 6, lane = tid & 63;
  const int bh = blockIdx.y, b = bh >> 4, h = bh & 15;
  const int q0 = blockIdx.x * 128 + wid * 16;
  const int rsel = lane & 15, grp = lane >> 4, ksel = grp * 8;
  const int swz = rsel & 7;
  const uint* fl = flags + (b << 10) + ((q0 >> 6) << 5);
  const ushort* kpan = Kb + (size_t)bh * CT * CDK;
  const ushort* vpan = Vt + (size_t)bh * CDK * CT;

  // staging: 512 threads cover 64 rows x 8 col-chunks; source pre-swizzled (rule 21)
  const int strow = tid >> 3, stc = (tid & 7) ^ (strow & 7);

  auto stageK = [&](int bu, int k0) {
    gl2lds16(&kpan[(size_t)(k0 + strow) * CDK + stc * 8], &Ks[bu][(size_t)wid * 512]);
  };
  auto stageV = [&](int bu, int k0) {
    gl2lds16(&vpan[(size_t)strow * CT + k0 + stc * 8], &Vs[bu][(size_t)wid * 512]);
  };

  // Q fragments (B-operand): lane holds Q[q0+rsel][dk = grp*8..+8] halves
  short8 qa0, qa1;
  {
    const ushort* qrow = Qb + ((size_t)bh * CT + q0 + rsel) * CDK;
    qa0 = *reinterpret_cast<const short8*>(qrow + ksel);
    qa1 = *reinterpret_cast<const short8*>(qrow + 32 + ksel);
  }

  const int* mrow = mask + (size_t)b * CT * CT;
  const int qme = q0 + rsel; // this lane's q row (l-sum, mask)

  // ---- pass 1: l[q] = sum_k exp2(S) ; scalar per lane, dbuf K staging ----
  float l_lane = 0.f;
  stageK(0, 0);
  __syncthreads();
  int bu = 0;
  for (int kt = 0; kt < 32; ++kt) {
    const int k0 = kt * 64;
    if (kt + 1 < 32) stageK(bu ^ 1, k0 + 64);
    const uint f = fl[kt];
    for (int ni = 0; ni < 4; ++ni) {
      const int krow = ni * 16 + rsel;
      short8 kb0 = *reinterpret_cast<short8*>(&Ks[bu][krow * 64 + ((grp    ) ^ swz) * 8]);
      short8 kb1 = *reinterpret_cast<short8*>(&Ks[bu][krow * 64 + ((grp + 4) ^ swz) * 8]);
      f32x4 z = {0.f, 0.f, 0.f, 0.f};
      z = __builtin_amdgcn_mfma_f32_16x16x32_bf16(kb0, qa0, z, 0, 0, 0);
      z = __builtin_amdgcn_mfma_f32_16x16x32_bf16(kb1, qa1, z, 0, 0, 0);
      if (f) {
        l_lane += exp2f(z[0]) + exp2f(z[1]) + exp2f(z[2]) + exp2f(z[3]);
      } else {
        const int kb_ = k0 + ni * 16 + grp * 4;
        for (int r = 0; r < 4; ++r)
          l_lane += mrow[(size_t)qme * CT + kb_ + r] ? exp2f(z[r]) : 0.f;
      }
    }
    __syncthreads();
    bu ^= 1;
  }
  // reduce over the 4 grp-lanes sharing this rsel
  l_lane += __shfl_xor(l_lane, 16, 64);
  l_lane += __shfl_xor(l_lane, 32, 64);
  const float ll = __log2f(l_lane); // p_scaled = exp2(z - ll) == exp2(z)/l

  // ---- pass 2: recompute, P (prescaled) -> LDS f32, coalesced NT attn store, PV ----
  f32x4 oacc[4];
  for (int nd = 0; nd < 4; ++nd) oacc[nd] = f32x4{0.f, 0.f, 0.f, 0.f};
  float* apan = attn_out + (size_t)bh * CT * CT;
  float* pf = &Pf[wid][0];

  stageK(0, 0);
  stageV(0, 0);
  __syncthreads();
  bu = 0;
  for (int kt = 0; kt < 32; ++kt) {
    const int k0 = kt * 64;
    if (kt + 1 < 32) { stageK(bu ^ 1, k0 + 64); stageV(bu ^ 1, k0 + 64); }
    const uint f = fl[kt];
    for (int ni = 0; ni < 4; ++ni) {
      const int krow = ni * 16 + rsel;
      short8 kb0 = *reinterpret_cast<short8*>(&Ks[bu][krow * 64 + ((grp    ) ^ swz) * 8]);
      short8 kb1 = *reinterpret_cast<short8*>(&Ks[bu][krow * 64 + ((grp + 4) ^ swz) * 8]);
      f32x4 z = {0.f, 0.f, 0.f, 0.f};
      z = __builtin_amdgcn_mfma_f32_16x16x32_bf16(kb0, qa0, z, 0, 0, 0);
      z = __builtin_amdgcn_mfma_f32_16x16x32_bf16(kb1, qa1, z, 0, 0, 0);
      float p0, p1, p2, p3;
      if (f) {
        p0 = exp2f(z[0] - ll); p1 = exp2f(z[1] - ll);
        p2 = exp2f(z[2] - ll); p3 = exp2f(z[3] - ll);
      } else {
        const size_t mb = (size_t)qme * CT + k0 + ni * 16 + grp * 4;
        p0 = mrow[mb + 0] ? exp2f(z[0] - ll) : 0.f;
        p1 = mrow[mb + 1] ? exp2f(z[1] - ll) : 0.f;
        p2 = mrow[mb + 2] ? exp2f(z[2] - ll) : 0.f;
        p3 = mrow[mb + 3] ? exp2f(z[3] - ll) : 0.f;
      }
      // Pf[row=rsel][chunk = ni*4+grp], chunk XOR-swizzled by row&7
      *reinterpret_cast<f32x4*>(&pf[rsel * 64 + (((ni * 4 + grp) ^ swz) << 2)]) =
          f32x4{p0, p1, p2, p3};
    }
    // cooperative attn store: per instruction 16 lanes x 16B = 256B contiguous per row
    for (int rr = 0; rr < 4; ++rr) {
      const int row = rr * 4 + grp;
      f32x4 v = *reinterpret_cast<f32x4*>(&pf[row * 64 + ((rsel ^ (row & 7)) << 2)]);
      __builtin_nontemporal_store(v,
          reinterpret_cast<f32x4*>(apan + (size_t)(q0 + row) * CT + k0 + rsel * 4));
    }
    // PV A-fragment: P[q=rsel][k=ksel..+8] per 32-k half, from swizzled chunks
    f32x4 a0 = *reinterpret_cast<f32x4*>(&pf[rsel * 64 + (((2 * grp    ) ^ swz) << 2)]);
    f32x4 a1 = *reinterpret_cast<f32x4*>(&pf[rsel * 64 + (((2 * grp + 1) ^ swz) << 2)]);
    f32x4 a2 = *reinterpret_cast<f32x4*>(&pf[rsel * 64 + (((2 * grp + 8) ^ swz) << 2)]);
    f32x4 a3 = *reinterpret_cast<f32x4*>(&pf[rsel * 64 + (((2 * grp + 9) ^ swz) << 2)]);
    short8 pa0 = {(short)f2bf(a0[0]), (short)f2bf(a0[1]), (short)f2bf(a0[2]), (short)f2bf(a0[3]),
                  (short)f2bf(a1[0]), (short)f2bf(a1[1]), (short)f2bf(a1[2]), (short)f2bf(a1[3])};
    short8 pa1 = {(short)f2bf(a2[0]), (short)f2bf(a2[1]), (short)f2bf(a2[2]), (short)f2bf(a2[3]),
                  (short)f2bf(a3[0]), (short)f2bf(a3[1]), (short)f2bf(a3[2]), (short)f2bf(a3[3])};
    for (int nd = 0; nd < 4; ++nd) {
      const int vrow = nd * 16 + rsel;
      short8 vb0 = *reinterpret_cast<short8*>(&Vs[bu][vrow * 64 + ((grp    ) ^ swz) * 8]);
      short8 vb1 = *reinterpret_cast<short8*>(&Vs[bu][vrow * 64 + ((grp + 4) ^ swz) * 8]);
      oacc[nd] = __builtin_amdgcn_mfma_f32_16x16x32_bf16(pa0, vb0, oacc[nd], 0, 0, 0);
      oacc[nd] = __builtin_amdgcn_mfma_f32_16x16x32_bf16(pa1, vb1, oacc[nd], 0, 0, 0);
    }
    __syncthreads();
    bu ^= 1;
  }

  // oh write: P was pre-scaled, so oacc is already normalized
  for (int nd = 0; nd < 4; ++nd)
    for (int r = 0; r < 4; ++r) {
      int q = q0 + grp * 4 + r, d = nd * 16 + rsel;
      oh[((size_t)b * CT + q) * CD + h * CDK + d] = f2bf(oacc[nd][r]);
    }
}

// ---------------- launcher ----------------
extern "C" void kernel_launch(void* const* d_in, const int* in_sizes, int n_in,
                              void* d_out, int out_size, void* d_ws, size_t ws_size,
                              hipStream_t stream)
{
  const float* x_q  = (const float*)d_in[0];
  const float* x_kv = (const float*)d_in[1];
  const int*   mask = (const int*)d_in[2];
  const float* Wq = (const float*)d_in[3];
  const float* bq = (const float*)d_in[4];
  const float* Wk = (const float*)d_in[5];
  const float* bk = (const float*)d_in[6];
  const float* Wv = (const float*)d_in[7];
  const float* bv = (const float*)d_in[8];
  const float* Wo = (const float*)d_in[9];
  const float* bo = (const float*)d_in[10];

  float* out  = (float*)d_out;
  float* attn = out + (size_t)CB * CT * CD;

  char* w = (char*)d_ws;
  auto alloc = [&](size_t bytes) { char* p = w; w += (bytes + 255) & ~(size_t)255; return p; };
  ushort* xq_bf  = (ushort*)alloc((size_t)CM * CD * 2);
  ushort* xkv_bf = (ushort*)alloc((size_t)CM * CD * 2);
  ushort* Wq_bf  = (ushort*)alloc((size_t)CD * CD * 2);
  ushort* Wk_bf  = (ushort*)alloc((size_t)CD * CD * 2); // Wk_bf/Wv_bf contiguous (2MB each, 256-aligned)
  ushort* Wv_bf  = (ushort*)alloc((size_t)CD * CD * 2);
  ushort* Wo_bf  = (ushort*)alloc((size_t)CD * CD * 2);
  ushort* Q_bf   = (ushort*)alloc((size_t)CM * CD * 2);
  ushort* K_bf   = (ushort*)alloc((size_t)CM * CD * 2);
  ushort* Vt_bf  = (ushort*)alloc((size_t)CM * CD * 2);
  ushort* oh_bf  = (ushort*)alloc((size_t)CM * CD * 2);
  uint*   mflags = (uint*)alloc(2048 * sizeof(uint));

  {
    const int nx = CM * CD, nw = CD * CD;
    const int total_quads = (2 * nx + 4 * nw) / 4;
    const int blocks = (total_quads + 255) / 256;
    hipLaunchKernelGGL(cvt_all_kernel, dim3(blocks), dim3(256), 0, stream,
                       x_q, xq_bf, nx, x_kv, xkv_bf, nx,
                       Wq, Wq_bf, nw, Wk, Wk_bf, nw,
                       Wv, Wv_bf, nw, Wo, Wo_bf, nw);
  }

  hipLaunchKernelGGL(mask_flags_kernel, dim3(2048), dim3(256), 0, stream, mask, mflags);

  hipLaunchKernelGGL(gemm_nt_kernel, dim3(CD / 64, CM / 128), dim3(256), 0, stream,
                     xq_bf, Wq_bf, bq, bq, (void*)Q_bf, nullptr, CM, CD, CD, 0, 0.125f * LOG2E);
  hipLaunchKernelGGL(gemm_nt_kernel, dim3(2 * CD / 64, CM / 128), dim3(256), 0, stream,
                     xkv_bf, Wk_bf, bk, bv, (void*)K_bf, (void*)Vt_bf, CM, 2 * CD, CD, 3, 1.0f);

  hipLaunchKernelGGL(attn_kernel, dim3(CT / 128, CB * CH), dim3(512), 0, stream,
                     Q_bf, K_bf, Vt_bf, mask, mflags, attn, oh_bf);

  hipLaunchKernelGGL(gemm_nt_kernel, dim3(CD / 64, CM / 128), dim3(256), 0, stream,
                     oh_bf, Wo_bf, bo, bo, d_out, nullptr, CM, CD, CD, 2, 1.0f);
}